// Round 9
// baseline (262.244 us; speedup 1.0000x reference)
//
#include <hip/hip_runtime.h>
#include <cstdint>
#include <cstddef>

typedef unsigned short u16;
typedef unsigned int u32;
typedef __attribute__((ext_vector_type(8))) short short8;
typedef __attribute__((ext_vector_type(4))) float f32x4;

#define T_SEQ 2048
#define BT_ROWS 16384

// ---------- helpers ----------
__device__ __forceinline__ u16 f2bf(float x) {
  union { float f; u32 u; } v; v.f = x;
  u32 r = v.u + 0x7fffu + ((v.u >> 16) & 1u);
  return (u16)(r >> 16);
}
// pack two floats -> two bf16 in one u32 (lo in low half)
__device__ __forceinline__ u32 pkbf(float lo, float hi) {
  union { float f; u32 u; } a, b; a.f = lo; b.f = hi;
  const u32 ra = a.u + 0x7fffu + ((a.u >> 16) & 1u);
  const u32 rb = b.u + 0x7fffu + ((b.u >> 16) & 1u);
  return __builtin_amdgcn_perm(rb, ra, 0x07060302);
}
__device__ __forceinline__ float wave_bcast_sum(float x) {
#pragma unroll
  for (int off = 32; off > 0; off >>= 1) x += __shfl_down(x, off);
  return __shfl(x, 0);
}
__device__ __forceinline__ void gl_lds16(const void* g, void* l) {
  __builtin_amdgcn_global_load_lds((const __attribute__((address_space(1))) u32*)g,
                                   (__attribute__((address_space(3))) u32*)l, 16, 0, 0);
}
// tanh-form GELU; |diff| vs erf ~3e-4
__device__ __forceinline__ float gelu_f(float x) {
  float z = 1.5957691216057308f * x * (1.0f + 0.044715f * x * x);
  float e = __expf(z);
  return x - x * __builtin_amdgcn_rcpf(1.0f + e);
}
// release-barrier: publish LDS writes, do NOT drain vmcnt (keep global loads flying)
__device__ __forceinline__ void lgkm_barrier() {
  asm volatile("s_waitcnt lgkmcnt(0)" ::: "memory");
  __builtin_amdgcn_s_barrier();
}

// ---------- transpose+convert all 3 weights + zero logits ----------
__global__ __launch_bounds__(256) void tcvt_all(const float* __restrict__ Wv,
                                                const float* __restrict__ Wa,
                                                const float* __restrict__ W1,
                                                u16* __restrict__ wvT,
                                                u16* __restrict__ waT,
                                                u16* __restrict__ w1T,
                                                float* __restrict__ logits) {
  int b = blockIdx.x;
  if (b >= 1216) {  // 64 blocks zero the 16384-float logits buffer
    logits[(b - 1216) * 256 + threadIdx.x] = 0.0f;
    return;
  }
  __shared__ float tile[32][33];
  const float* in; u16* out; int K, N, bx, by;
  if (b < 256)      { in = Wv; out = wvT; K = 1024; N = 256;  bx = b & 31;  by = b >> 5; }
  else if (b < 448) { b -= 256; in = Wa; out = waT; K = 768; N = 256;  bx = b % 24; by = b / 24; }
  else              { b -= 448; in = W1; out = w1T; K = 768; N = 1024; bx = b % 24; by = b / 24; }
  const int k0 = bx * 32, n0 = by * 32;
  const int tx = threadIdx.x & 31, ty = threadIdx.x >> 5;
#pragma unroll
  for (int r = 0; r < 4; r++)
    tile[ty + r * 8][tx] = in[(size_t)(k0 + ty + r * 8) * N + n0 + tx];
  __syncthreads();
#pragma unroll
  for (int r = 0; r < 4; r++)
    out[(size_t)(n0 + ty + r * 8) * K + k0 + tx] = f2bf(tile[tx][ty + r * 8]);
}

// ---------- projection GEMM with FUSED LayerNorm, tile 64x256 (r3 config) ----------
// Mt=64, 256 thr, grid 512 (2 blocks/CU) — empirically the best config (58 µs,
// stable across 4 runs, at the per-CU vmem request cap). K-phase rotation +
// B-in-registers + lgkm-only barrier. DO NOT retile (r4/r5 both regressed).
template <int K>
__device__ __forceinline__ void proj_body(const float* __restrict__ A,
                                          const u16* __restrict__ Bt,
                                          const float* __restrict__ bias,
                                          float* __restrict__ C,
                                          int m0, u16* As, int k0) {
  constexpr int NT = K / 64;
  const int tid = threadIdx.x;
  const int wave = tid >> 6, lane = tid & 63, qm = lane & 15, quad = lane >> 4;
  const int cw = wave * 64;   // wave owns a 64-col quarter, all 64 rows

  // A register staging: thread owns row ar = tid>>2, 16 consecutive floats.
  const int ar = tid >> 2;
  const float* Arow = A + (size_t)(m0 + ar) * K + (tid & 3) * 4;
  int awAddr[4];
#pragma unroll
  for (int g = 0; g < 4; g++) {
    const int cg = ((tid & 3) >> 1) + 2 * g;
    awAddr[g] = ar * 64 + ((cg ^ (ar & 7)) * 8) + (tid & 1) * 4;
  }
  // B fragment row pointers (row = output col); chunk offset = quad*8 + s*32
  const u16* brow[4];
#pragma unroll
  for (int j = 0; j < 4; j++)
    brow[j] = Bt + (size_t)(cw + j * 16 + qm) * K + quad * 8;

  f32x4 acc[4][4] = {};
  short8 bfrag[2][8];
  float4 p[4];

  int koff = k0;   // current K-tile element offset (circular)

  // ---- prologue: A(koff) -> As[0], B(koff) -> bfrag[0] ----
#pragma unroll
  for (int g = 0; g < 4; g++) p[g] = *(const float4*)(Arow + koff + g * 16);
#pragma unroll
  for (int s = 0; s < 2; s++)
#pragma unroll
    for (int j = 0; j < 4; j++)
      bfrag[0][s * 4 + j] = *(const short8*)(brow[j] + koff + s * 32);
#pragma unroll
  for (int g = 0; g < 4; g++) {
    uint2 w; w.x = pkbf(p[g].x, p[g].y); w.y = pkbf(p[g].z, p[g].w);
    *(uint2*)&As[awAddr[g]] = w;
  }
  lgkm_barrier();

#pragma unroll
  for (int t = 0; t < NT; t++) {
    const int cb = t & 1, nb = cb ^ 1;
    int knext = koff + 64;
    if (knext == K) knext = 0;   // circular K walk
    if (t + 1 < NT) {  // issue next-tile loads; they fly across the barrier
#pragma unroll
      for (int g = 0; g < 4; g++)
        p[g] = *(const float4*)(Arow + knext + g * 16);
#pragma unroll
      for (int s = 0; s < 2; s++)
#pragma unroll
        for (int j = 0; j < 4; j++)
          bfrag[nb][s * 4 + j] = *(const short8*)(brow[j] + knext + s * 32);
    }
#pragma unroll
    for (int s = 0; s < 2; s++) {
      short8 af[4];
#pragma unroll
      for (int i = 0; i < 4; i++) {
        const int r = i * 16 + qm;
        af[i] = *(const short8*)&As[cb * 4096 + r * 64 + ((s * 4 + quad) ^ (r & 7)) * 8];
      }
      __builtin_amdgcn_s_setprio(1);
#pragma unroll
      for (int i = 0; i < 4; i++)
#pragma unroll
        for (int j = 0; j < 4; j++)
          acc[i][j] = __builtin_amdgcn_mfma_f32_16x16x32_bf16(
              af[i], bfrag[cb][s * 4 + j], acc[i][j], 0, 0, 0);
      __builtin_amdgcn_s_setprio(0);
    }
    if (t + 1 < NT) {  // convert+publish next A tile (p landed under MFMAs)
#pragma unroll
      for (int g = 0; g < 4; g++) {
        uint2 w; w.x = pkbf(p[g].x, p[g].y); w.y = pkbf(p[g].z, p[g].w);
        *(uint2*)&As[nb * 4096 + awAddr[g]] = w;
      }
      lgkm_barrier();
    }
    koff = knext;
  }

  // ---- fused bias + LayerNorm epilogue over 64 rows ----
  float bcol[4];
#pragma unroll
  for (int j = 0; j < 4; j++) bcol[j] = bias[cw + j * 16 + qm];
#pragma unroll
  for (int i = 0; i < 4; i++)
#pragma unroll
    for (int j = 0; j < 4; j++)
#pragma unroll
      for (int r = 0; r < 4; r++)
        acc[i][j][r] += bcol[j];
  float s1[4][4], s2[4][4];
#pragma unroll
  for (int i = 0; i < 4; i++)
#pragma unroll
    for (int r = 0; r < 4; r++) {
      float a1 = 0, a2 = 0;
#pragma unroll
      for (int j = 0; j < 4; j++) { a1 += acc[i][j][r]; a2 += acc[i][j][r] * acc[i][j][r]; }
#pragma unroll
      for (int off = 1; off < 16; off <<= 1) {
        a1 += __shfl_xor(a1, off);
        a2 += __shfl_xor(a2, off);
      }
      s1[i][r] = a1; s2[i][r] = a2;
    }
  __syncthreads();          // all waves done with K-loop LDS before scratch reuse
  float* red = (float*)As;
  if (qm == 0) {
#pragma unroll
    for (int i = 0; i < 4; i++)
#pragma unroll
      for (int r = 0; r < 4; r++) {
        const int row = i * 16 + quad * 4 + r;
        red[row * 8 + wave * 2] = s1[i][r];
        red[row * 8 + wave * 2 + 1] = s2[i][r];
      }
  }
  __syncthreads();
#pragma unroll
  for (int i = 0; i < 4; i++)
#pragma unroll
    for (int r = 0; r < 4; r++) {
      const int row = i * 16 + quad * 4 + r;   // D: row = quad*4 + reg (+ i*16)
      const float4 q1 = *(const float4*)&red[row * 8];
      const float4 q2 = *(const float4*)&red[row * 8 + 4];
      const float st = q1.x + q1.z + q2.x + q2.z;
      const float st2 = q1.y + q1.w + q2.y + q2.w;
      const float mu = st * (1.0f / 256.0f);
      const float var = st2 * (1.0f / 256.0f) - mu * mu;
      const float inv = rsqrtf(var + 1e-5f);
#pragma unroll
      for (int j = 0; j < 4; j++)
        C[(size_t)(m0 + row) * 256 + cw + j * 16 + qm] = (acc[i][j][r] - mu) * inv;
    }
}

__global__ __launch_bounds__(256, 2) void proj_ln(const float* __restrict__ Vin,
                                                  const float* __restrict__ Ain,
                                                  const u16* __restrict__ wvT,
                                                  const u16* __restrict__ waT,
                                                  const float* __restrict__ bv,
                                                  const float* __restrict__ ba,
                                                  float* __restrict__ vOut,
                                                  float* __restrict__ aOut) {
  __shared__ __align__(16) u16 As[2][64 * 64];   // 16 KB total (A dbuf, bf16)
  int b = blockIdx.x;
  if (b < 256)
    proj_body<1024>(Vin, wvT, bv, vOut, b * 64, &As[0][0], (b & 15) * 64);
  else {
    b -= 256;
    proj_body<768>(Ain, waT, ba, aOut, b * 64, &As[0][0], (b % 12) * 64);
  }
}

// ---------- MLP GEMM v4: proj_ln structure ported. Tile 128x256, 256 thr,
// grid (4,128)=512 = 2 blocks/CU. B (w1T, 1.5 MB, L2-resident) direct to
// registers one K-step ahead; A (xb, already bf16 -> staging is a pure 16B
// copy) reg->LDS dbuf; lgkm-only barrier so vmem NEVER drains in the loop
// (the r0-r8 gemms all drained vmcnt(0) per step -> 1.8-3.5 TB/s; proj's
// structure measures 6.4). K-phase rotation de-camps channels. ----
__global__ __launch_bounds__(256, 2) void gemm_gelu_w2(const u16* __restrict__ Axb,
                                                       const u16* __restrict__ Bt,
                                                       const float* __restrict__ b1,
                                                       const float* __restrict__ W2,
                                                       float* __restrict__ logits) {
  constexpr int K = 768;
  constexpr int NT = K / 64;   // 12
  __shared__ __align__(16) u16 As[2][128 * 64];   // 32 KB total (A dbuf)
  const int tid = threadIdx.x;
  const int n0 = blockIdx.x * 256;   // 4 n-tiles
  const int m0 = blockIdx.y * 128;   // 128 m-tiles
  const int wave = tid >> 6, lane = tid & 63, qm = lane & 15, quad = lane >> 4;
  const int cw = wave * 64;   // wave owns a 64-col slice, all 128 rows

  // A staging: thread owns row ar = tid>>1, 64B half (tid&1) of the row's
  // 128B K-step chunk. 2 threads/row -> fully coalesced 128B row segments.
  const int ar = tid >> 1;
  const u16* Arow = Axb + (size_t)(m0 + ar) * K + (tid & 1) * 32;
  int awAddr[4];
#pragma unroll
  for (int c = 0; c < 4; c++) {
    const int cg = (tid & 1) * 4 + c;            // global 16B-chunk index 0..7
    awAddr[c] = ar * 64 + ((cg ^ (ar & 7)) * 8); // xor-8 swizzle (proj-proven)
  }
  // B fragment row pointers (row = output col); chunk offset = quad*8 + s*32
  const u16* brow[4];
#pragma unroll
  for (int j = 0; j < 4; j++)
    brow[j] = Bt + (size_t)(n0 + cw + j * 16 + qm) * K + quad * 8;

  f32x4 acc[8][4] = {};
  short8 bfrag[2][8];
  uint4 p[4];

  int koff = (blockIdx.y % NT) * 64;   // K-phase rotation (circular walk)

  // ---- prologue: A(koff) -> As[0], B(koff) -> bfrag[0] ----
#pragma unroll
  for (int c = 0; c < 4; c++) p[c] = *(const uint4*)(Arow + koff + c * 8);
#pragma unroll
  for (int s = 0; s < 2; s++)
#pragma unroll
    for (int j = 0; j < 4; j++)
      bfrag[0][s * 4 + j] = *(const short8*)(brow[j] + koff + s * 32);
#pragma unroll
  for (int c = 0; c < 4; c++) *(uint4*)&As[0][awAddr[c]] = p[c];
  lgkm_barrier();

#pragma unroll
  for (int t = 0; t < NT; t++) {
    const int cb = t & 1, nb = cb ^ 1;
    int knext = koff + 64;
    if (knext == K) knext = 0;
    if (t + 1 < NT) {  // issue next-tile loads; they fly across the barrier
#pragma unroll
      for (int c = 0; c < 4; c++) p[c] = *(const uint4*)(Arow + knext + c * 8);
#pragma unroll
      for (int s = 0; s < 2; s++)
#pragma unroll
        for (int j = 0; j < 4; j++)
          bfrag[nb][s * 4 + j] = *(const short8*)(brow[j] + knext + s * 32);
    }
#pragma unroll
    for (int s = 0; s < 2; s++) {
      short8 af[8];
#pragma unroll
      for (int i = 0; i < 8; i++) {
        const int r = i * 16 + qm;
        af[i] = *(const short8*)&As[cb][r * 64 + ((s * 4 + quad) ^ (r & 7)) * 8];
      }
      __builtin_amdgcn_s_setprio(1);
#pragma unroll
      for (int i = 0; i < 8; i++)
#pragma unroll
        for (int j = 0; j < 4; j++)
          acc[i][j] = __builtin_amdgcn_mfma_f32_16x16x32_bf16(
              af[i], bfrag[cb][s * 4 + j], acc[i][j], 0, 0, 0);
      __builtin_amdgcn_s_setprio(0);
    }
    if (t + 1 < NT) {  // publish next A tile (pure copy, loads landed under MFMAs)
#pragma unroll
      for (int c = 0; c < 4; c++) *(uint4*)&As[nb][awAddr[c]] = p[c];
      lgkm_barrier();
    }
    koff = knext;
  }

  // epilogue: partial logit = sum_j gelu(acc+b1)*W2; reduce over qm lanes; 1 atomic/row/wave
  float w2j[4], bc[4];
#pragma unroll
  for (int j = 0; j < 4; j++) {
    const int col = n0 + cw + j * 16 + qm;
    w2j[j] = W2[col];
    bc[j] = b1[col];
  }
#pragma unroll
  for (int i = 0; i < 8; i++) {
#pragma unroll
    for (int r = 0; r < 4; r++) {
      float pl = 0.0f;
#pragma unroll
      for (int j = 0; j < 4; j++)
        pl += gelu_f(acc[i][j][r] + bc[j]) * w2j[j];
      pl += __shfl_xor(pl, 1);
      pl += __shfl_xor(pl, 2);
      pl += __shfl_xor(pl, 4);
      pl += __shfl_xor(pl, 8);
      if (qm == 0)
        atomicAdd(&logits[m0 + i * 16 + quad * 4 + r], pl);
    }
  }
}

// ---------- fused: fractional shift + window avg + l2norm(actx,v) + concat ----------
// Naive grid-4096 form (proven; r7's sliding-conv regressed).
__global__ __launch_bounds__(256) void shift_norm(const float* __restrict__ a,
                                                  const float* __restrict__ v,
                                                  float* __restrict__ actx,
                                                  u16* __restrict__ xb,
                                                  const float* __restrict__ theta) {
  const int row = blockIdx.x * 4 + (threadIdx.x >> 6);
  const int lane = threadIdx.x & 63;
  const int d4 = lane * 4;
  const int bb = row >> 11;
  const int t = row & (T_SEQ - 1);
  const float th = fminf(fmaxf(theta[0], -12.0f), 12.0f);
  const float delta = 2.0f + 4.0f * (1.0f / (1.0f + expf(-th)));
  const float dl = fminf(fmaxf(delta, 0.0f), (float)(T_SEQ - 1));
  const float nf = floorf(dl);
  const float alpha = dl - nf;
  const int ni = (int)nf;
  const float center = fminf(fmaxf((float)t + delta, 0.0f), (float)t);
  float sx = 0, sy = 0, sz = 0, sw = 0, cnt = 0.0f;
  const float* ab = a + (size_t)bb * T_SEQ * 256;
#pragma unroll
  for (int j = 0; j < 6; j++) {
    const int tau = t - 5 + j;
    if (tau < 0) continue;
    if (fabsf((float)tau - center) > 5.0f) continue;
    cnt += 1.0f;
    const int i0 = min(max(tau - ni, 0), T_SEQ - 1);
    const int i1 = min(i0 + 1, T_SEQ - 1);
    const float4 a0 = *(const float4*)&ab[(size_t)i0 * 256 + d4];
    const float4 a1 = *(const float4*)&ab[(size_t)i1 * 256 + d4];
    sx += a0.x + alpha * (a1.x - a0.x);
    sy += a0.y + alpha * (a1.y - a0.y);
    sz += a0.z + alpha * (a1.z - a0.z);
    sw += a0.w + alpha * (a1.w - a0.w);
  }
  const float sc = 1.0f / fmaxf(cnt, 1e-8f);
  float4 o; o.x = sx * sc; o.y = sy * sc; o.z = sz * sc; o.w = sw * sc;
  *(float4*)&actx[(size_t)row * 256 + d4] = o;
  const float4 vv = *(const float4*)&v[(size_t)row * 256 + d4];
  float sa2 = o.x * o.x + o.y * o.y + o.z * o.z + o.w * o.w;
  float sv2 = vv.x * vv.x + vv.y * vv.y + vv.z * vv.z + vv.w * vv.w;
  sa2 = wave_bcast_sum(sa2);
  sv2 = wave_bcast_sum(sv2);
  const float ia = 1.0f / fmaxf(sqrtf(sa2), 1e-8f);
  const float iv = 1.0f / fmaxf(sqrtf(sv2), 1e-8f);
  const float anx = o.x * ia, any_ = o.y * ia, anz = o.z * ia, anw = o.w * ia;
  const float vnx = vv.x * iv, vny = vv.y * iv, vnz = vv.z * iv, vnw = vv.w * iv;
  u16* xr = xb + (size_t)row * 768;
  u32 pa[2] = {pkbf(anx, any_), pkbf(anz, anw)};
  u32 pv[2] = {pkbf(vnx, vny), pkbf(vnz, vnw)};
  u32 pp[2] = {pkbf(anx * vnx, any_ * vny), pkbf(anz * vnz, anw * vnw)};
  *(uint2*)&xr[d4] = *(uint2*)pa;
  *(uint2*)&xr[256 + d4] = *(uint2*)pv;
  *(uint2*)&xr[512 + d4] = *(uint2*)pp;
}

// ---------- gate + mix ----------
__global__ __launch_bounds__(256) void gate_mix(const float* __restrict__ logits,
                                                const float* __restrict__ b2,
                                                const float* __restrict__ actx,
                                                const float* __restrict__ v,
                                                float* __restrict__ out) {
  const int row = blockIdx.x * 4 + (threadIdx.x >> 6);
  const int lane = threadIdx.x & 63;
  const float l = fminf(fmaxf(logits[row] + b2[0], -12.0f), 12.0f);
  float g = 1.0f / (1.0f + expf(-l));
  g = fminf(fmaxf(g, 0.05f), 0.95f);
  const float4 aa = *(const float4*)&actx[(size_t)row * 256 + lane * 4];
  const float4 vv = *(const float4*)&v[(size_t)row * 256 + lane * 4];
  float4 o;
  o.x = g * aa.x + (1.0f - g) * vv.x;
  o.y = g * aa.y + (1.0f - g) * vv.y;
  o.z = g * aa.z + (1.0f - g) * vv.z;
  o.w = g * aa.w + (1.0f - g) * vv.w;
  *(float4*)&out[(size_t)row * 256 + lane * 4] = o;
}

// ---------- launch ----------
extern "C" void kernel_launch(void* const* d_in, const int* in_sizes, int n_in,
                              void* d_out, int out_size, void* d_ws, size_t ws_size,
                              hipStream_t stream) {
  const float* video = (const float*)d_in[0];
  const float* audio = (const float*)d_in[1];
  const float* Wv    = (const float*)d_in[2];
  const float* bv    = (const float*)d_in[3];
  const float* Wa    = (const float*)d_in[4];
  const float* ba    = (const float*)d_in[5];
  const float* theta = (const float*)d_in[6];
  const float* W1    = (const float*)d_in[7];
  const float* b1    = (const float*)d_in[8];
  const float* W2    = (const float*)d_in[9];
  const float* b2    = (const float*)d_in[10];
  float* out = (float*)d_out;
  char* ws = (char*)d_ws;

  const size_t OFF_WVT = 0;          // [256][1024] bf16 = 512 KB
  const size_t OFF_WAT = 524288;     // [256][768]  bf16 = 384 KB
  const size_t OFF_W1T = 917504;     // [1024][768] bf16 = 1.5 MB
  const size_t OFF_LOG = 2490368;    // [16384] f32 = 64 KB
  const size_t OFF_V   = 2555904;    // [16384][256] f32 = 16 MB (LN'd v)
  const size_t OFF_A   = 19333120;   // [16384][256] f32 = 16 MB (LN'd a)
  const size_t OFF_ACTX= 36110336;   // [16384][256] f32 = 16 MB
  const size_t OFF_XB  = 52887552;   // [16384][768] bf16 = 24 MB

  u16* wvT = (u16*)(ws + OFF_WVT);
  u16* waT = (u16*)(ws + OFF_WAT);
  u16* w1T = (u16*)(ws + OFF_W1T);
  float* logits = (float*)(ws + OFF_LOG);
  float* v    = (float*)(ws + OFF_V);
  float* a    = (float*)(ws + OFF_A);
  float* actx = (float*)(ws + OFF_ACTX);
  u16* xb = (u16*)(ws + OFF_XB);

  tcvt_all<<<1280, 256, 0, stream>>>(Wv, Wa, W1, wvT, waT, w1T, logits);
  proj_ln<<<512, 256, 0, stream>>>(video, audio, wvT, waT, bv, ba, v, a);
  shift_norm<<<BT_ROWS / 4, 256, 0, stream>>>(a, v, actx, xb, theta);
  gemm_gelu_w2<<<dim3(4, BT_ROWS / 128), 256, 0, stream>>>(xb, w1T, b1, W2, logits);
  gate_mix<<<BT_ROWS / 4, 256, 0, stream>>>(logits, b2, actx, v, out);
}

// Round 12
// 232.160 us; speedup vs baseline: 1.1296x; 1.1296x over previous
//
#include <hip/hip_runtime.h>
#include <cstdint>
#include <cstddef>

typedef unsigned short u16;
typedef unsigned int u32;
typedef __attribute__((ext_vector_type(8))) short short8;
typedef __attribute__((ext_vector_type(4))) float f32x4;

#define T_SEQ 2048
#define BT_ROWS 16384

// ---------- helpers ----------
__device__ __forceinline__ u16 f2bf(float x) {
  union { float f; u32 u; } v; v.f = x;
  u32 r = v.u + 0x7fffu + ((v.u >> 16) & 1u);
  return (u16)(r >> 16);
}
// pack two floats -> two bf16 in one u32 (lo in low half)
__device__ __forceinline__ u32 pkbf(float lo, float hi) {
  union { float f; u32 u; } a, b; a.f = lo; b.f = hi;
  const u32 ra = a.u + 0x7fffu + ((a.u >> 16) & 1u);
  const u32 rb = b.u + 0x7fffu + ((b.u >> 16) & 1u);
  return __builtin_amdgcn_perm(rb, ra, 0x07060302);
}
__device__ __forceinline__ float wave_bcast_sum(float x) {
#pragma unroll
  for (int off = 32; off > 0; off >>= 1) x += __shfl_down(x, off);
  return __shfl(x, 0);
}
__device__ __forceinline__ void gl_lds16(const void* g, void* l) {
  __builtin_amdgcn_global_load_lds((const __attribute__((address_space(1))) u32*)g,
                                   (__attribute__((address_space(3))) u32*)l, 16, 0, 0);
}
// tanh-form GELU; |diff| vs erf ~3e-4
__device__ __forceinline__ float gelu_f(float x) {
  float z = 1.5957691216057308f * x * (1.0f + 0.044715f * x * x);
  float e = __expf(z);
  return x - x * __builtin_amdgcn_rcpf(1.0f + e);
}
// release-barrier: publish LDS writes, do NOT drain vmcnt (keep global loads flying)
__device__ __forceinline__ void lgkm_barrier() {
  asm volatile("s_waitcnt lgkmcnt(0)" ::: "memory");
  __builtin_amdgcn_s_barrier();
}

// ---------- transpose+convert all 3 weights + zero logits ----------
__global__ __launch_bounds__(256) void tcvt_all(const float* __restrict__ Wv,
                                                const float* __restrict__ Wa,
                                                const float* __restrict__ W1,
                                                u16* __restrict__ wvT,
                                                u16* __restrict__ waT,
                                                u16* __restrict__ w1T,
                                                float* __restrict__ logits) {
  int b = blockIdx.x;
  if (b >= 1216) {  // 64 blocks zero the 16384-float logits buffer
    logits[(b - 1216) * 256 + threadIdx.x] = 0.0f;
    return;
  }
  __shared__ float tile[32][33];
  const float* in; u16* out; int K, N, bx, by;
  if (b < 256)      { in = Wv; out = wvT; K = 1024; N = 256;  bx = b & 31;  by = b >> 5; }
  else if (b < 448) { b -= 256; in = Wa; out = waT; K = 768; N = 256;  bx = b % 24; by = b / 24; }
  else              { b -= 448; in = W1; out = w1T; K = 768; N = 1024; bx = b % 24; by = b / 24; }
  const int k0 = bx * 32, n0 = by * 32;
  const int tx = threadIdx.x & 31, ty = threadIdx.x >> 5;
#pragma unroll
  for (int r = 0; r < 4; r++)
    tile[ty + r * 8][tx] = in[(size_t)(k0 + ty + r * 8) * N + n0 + tx];
  __syncthreads();
#pragma unroll
  for (int r = 0; r < 4; r++)
    out[(size_t)(n0 + ty + r * 8) * K + k0 + tx] = f2bf(tile[tx][ty + r * 8]);
}

// ---------- projection GEMM with FUSED LayerNorm, tile 64x256 (r3 config) ----------
// Mt=64, 256 thr, grid 512 (2 blocks/CU) — empirically the best config (58 µs,
// stable across 5 runs). K-phase rotation + B-in-registers + lgkm-only
// barrier. DO NOT retile (r4/r5 regressed).
template <int K>
__device__ __forceinline__ void proj_body(const float* __restrict__ A,
                                          const u16* __restrict__ Bt,
                                          const float* __restrict__ bias,
                                          float* __restrict__ C,
                                          int m0, u16* As, int k0) {
  constexpr int NT = K / 64;
  const int tid = threadIdx.x;
  const int wave = tid >> 6, lane = tid & 63, qm = lane & 15, quad = lane >> 4;
  const int cw = wave * 64;   // wave owns a 64-col quarter, all 64 rows

  // A register staging: thread owns row ar = tid>>2, 16 consecutive floats.
  const int ar = tid >> 2;
  const float* Arow = A + (size_t)(m0 + ar) * K + (tid & 3) * 4;
  int awAddr[4];
#pragma unroll
  for (int g = 0; g < 4; g++) {
    const int cg = ((tid & 3) >> 1) + 2 * g;
    awAddr[g] = ar * 64 + ((cg ^ (ar & 7)) * 8) + (tid & 1) * 4;
  }
  // B fragment row pointers (row = output col); chunk offset = quad*8 + s*32
  const u16* brow[4];
#pragma unroll
  for (int j = 0; j < 4; j++)
    brow[j] = Bt + (size_t)(cw + j * 16 + qm) * K + quad * 8;

  f32x4 acc[4][4] = {};
  short8 bfrag[2][8];
  float4 p[4];

  int koff = k0;   // current K-tile element offset (circular)

  // ---- prologue: A(koff) -> As[0], B(koff) -> bfrag[0] ----
#pragma unroll
  for (int g = 0; g < 4; g++) p[g] = *(const float4*)(Arow + koff + g * 16);
#pragma unroll
  for (int s = 0; s < 2; s++)
#pragma unroll
    for (int j = 0; j < 4; j++)
      bfrag[0][s * 4 + j] = *(const short8*)(brow[j] + koff + s * 32);
#pragma unroll
  for (int g = 0; g < 4; g++) {
    uint2 w; w.x = pkbf(p[g].x, p[g].y); w.y = pkbf(p[g].z, p[g].w);
    *(uint2*)&As[awAddr[g]] = w;
  }
  lgkm_barrier();

#pragma unroll
  for (int t = 0; t < NT; t++) {
    const int cb = t & 1, nb = cb ^ 1;
    int knext = koff + 64;
    if (knext == K) knext = 0;   // circular K walk
    if (t + 1 < NT) {  // issue next-tile loads; they fly across the barrier
#pragma unroll
      for (int g = 0; g < 4; g++)
        p[g] = *(const float4*)(Arow + knext + g * 16);
#pragma unroll
      for (int s = 0; s < 2; s++)
#pragma unroll
        for (int j = 0; j < 4; j++)
          bfrag[nb][s * 4 + j] = *(const short8*)(brow[j] + knext + s * 32);
    }
#pragma unroll
    for (int s = 0; s < 2; s++) {
      short8 af[4];
#pragma unroll
      for (int i = 0; i < 4; i++) {
        const int r = i * 16 + qm;
        af[i] = *(const short8*)&As[cb * 4096 + r * 64 + ((s * 4 + quad) ^ (r & 7)) * 8];
      }
      __builtin_amdgcn_s_setprio(1);
#pragma unroll
      for (int i = 0; i < 4; i++)
#pragma unroll
        for (int j = 0; j < 4; j++)
          acc[i][j] = __builtin_amdgcn_mfma_f32_16x16x32_bf16(
              af[i], bfrag[cb][s * 4 + j], acc[i][j], 0, 0, 0);
      __builtin_amdgcn_s_setprio(0);
    }
    if (t + 1 < NT) {  // convert+publish next A tile (p landed under MFMAs)
#pragma unroll
      for (int g = 0; g < 4; g++) {
        uint2 w; w.x = pkbf(p[g].x, p[g].y); w.y = pkbf(p[g].z, p[g].w);
        *(uint2*)&As[nb * 4096 + awAddr[g]] = w;
      }
      lgkm_barrier();
    }
    koff = knext;
  }

  // ---- fused bias + LayerNorm epilogue over 64 rows ----
  float bcol[4];
#pragma unroll
  for (int j = 0; j < 4; j++) bcol[j] = bias[cw + j * 16 + qm];
#pragma unroll
  for (int i = 0; i < 4; i++)
#pragma unroll
    for (int j = 0; j < 4; j++)
#pragma unroll
      for (int r = 0; r < 4; r++)
        acc[i][j][r] += bcol[j];
  float s1[4][4], s2[4][4];
#pragma unroll
  for (int i = 0; i < 4; i++)
#pragma unroll
    for (int r = 0; r < 4; r++) {
      float a1 = 0, a2 = 0;
#pragma unroll
      for (int j = 0; j < 4; j++) { a1 += acc[i][j][r]; a2 += acc[i][j][r] * acc[i][j][r]; }
#pragma unroll
      for (int off = 1; off < 16; off <<= 1) {
        a1 += __shfl_xor(a1, off);
        a2 += __shfl_xor(a2, off);
      }
      s1[i][r] = a1; s2[i][r] = a2;
    }
  __syncthreads();          // all waves done with K-loop LDS before scratch reuse
  float* red = (float*)As;
  if (qm == 0) {
#pragma unroll
    for (int i = 0; i < 4; i++)
#pragma unroll
      for (int r = 0; r < 4; r++) {
        const int row = i * 16 + quad * 4 + r;
        red[row * 8 + wave * 2] = s1[i][r];
        red[row * 8 + wave * 2 + 1] = s2[i][r];
      }
  }
  __syncthreads();
#pragma unroll
  for (int i = 0; i < 4; i++)
#pragma unroll
    for (int r = 0; r < 4; r++) {
      const int row = i * 16 + quad * 4 + r;   // D: row = quad*4 + reg (+ i*16)
      const float4 q1 = *(const float4*)&red[row * 8];
      const float4 q2 = *(const float4*)&red[row * 8 + 4];
      const float st = q1.x + q1.z + q2.x + q2.z;
      const float st2 = q1.y + q1.w + q2.y + q2.w;
      const float mu = st * (1.0f / 256.0f);
      const float var = st2 * (1.0f / 256.0f) - mu * mu;
      const float inv = rsqrtf(var + 1e-5f);
#pragma unroll
      for (int j = 0; j < 4; j++)
        C[(size_t)(m0 + row) * 256 + cw + j * 16 + qm] = (acc[i][j][r] - mu) * inv;
    }
}

__global__ __launch_bounds__(256, 2) void proj_ln(const float* __restrict__ Vin,
                                                  const float* __restrict__ Ain,
                                                  const u16* __restrict__ wvT,
                                                  const u16* __restrict__ waT,
                                                  const float* __restrict__ bv,
                                                  const float* __restrict__ ba,
                                                  float* __restrict__ vOut,
                                                  float* __restrict__ aOut) {
  __shared__ __align__(16) u16 As[2][64 * 64];   // 16 KB total (A dbuf, bf16)
  int b = blockIdx.x;
  if (b < 256)
    proj_body<1024>(Vin, wvT, bv, vOut, b * 64, &As[0][0], (b & 15) * 64);
  else {
    b -= 256;
    proj_body<768>(Ain, waT, ba, aOut, b * 64, &As[0][0], (b % 12) * 64);
  }
}

// ---------- MLP GEMM: r8 config restored EXACTLY (measured ~40 µs via
// round accounting): 256x256 byte-minimal tile (192 MB), grid (4,64)=256 =
// 1 block/CU, double-buffered LDS (128 KB) with vmcnt drain AFTER compute.
// r9's B-in-reg port moved 300 MB at the same rate -> slower. Bytes win. ----
__global__ __launch_bounds__(512, 2) void gemm_gelu_w2(const u16* __restrict__ Axb,
                                                       const u16* __restrict__ Bt,
                                                       const float* __restrict__ b1,
                                                       const float* __restrict__ W2,
                                                       float* __restrict__ logits) {
  constexpr int K = 768;
  constexpr int NT = K / 64;     // 12
  __shared__ u16 As[2][256 * 64];   // 64 KB
  __shared__ u16 Bs[2][256 * 64];   // 64 KB
  const int tid = threadIdx.x;       // 0..511
  const int n0 = blockIdx.x * 256;   // x = n: consecutive blocks share A m-tile
  const int m0 = blockIdx.y * 256;
  const int wave = tid >> 6, lane = tid & 63, qm = lane & 15, quad = lane >> 4;
  const int rw = (wave >> 1) * 64, cw = (wave & 1) * 128;

  // staging: instr g covers LDS rows (tid>>3)+g*64 linearly; in-row chunk
  // (tid&7); source pre-swizzled by xor-8 so swizzled reads land correctly.
  const u16* Ap[4];
  const u16* Bp[4];
#pragma unroll
  for (int g = 0; g < 4; g++) {
    const int r = (tid >> 3) + g * 64;
    const int cc = (tid & 7) ^ (r & 7);
    Ap[g] = Axb + (size_t)(m0 + r) * K + cc * 8;
    Bp[g] = Bt + (size_t)(n0 + r) * K + cc * 8;
  }

  f32x4 acc[4][8] = {};

  // ---- prologue: stage tile 0 into buffer 0, drain, barrier ----
#pragma unroll
  for (int g = 0; g < 4; g++) gl_lds16(Ap[g], &As[0][(tid + g * 512) * 8]);
#pragma unroll
  for (int g = 0; g < 4; g++) gl_lds16(Bp[g], &Bs[0][(tid + g * 512) * 8]);
  asm volatile("s_waitcnt vmcnt(0)" ::: "memory");
  __builtin_amdgcn_s_barrier();

#pragma unroll
  for (int t = 0; t < NT; t++) {
    const int cb = t & 1, nb = cb ^ 1;
    const int ktn = (t + 1) * 64;
    if (t + 1 < NT) {   // issue next-tile loads FIRST; compute hides latency
#pragma unroll
      for (int g = 0; g < 4; g++) gl_lds16(Ap[g] + ktn, &As[nb][(tid + g * 512) * 8]);
#pragma unroll
      for (int g = 0; g < 4; g++) gl_lds16(Bp[g] + ktn, &Bs[nb][(tid + g * 512) * 8]);
    }
#pragma unroll
    for (int s = 0; s < 2; s++) {
      short8 af[4], bfr[8];
#pragma unroll
      for (int i = 0; i < 4; i++) {
        const int r = rw + i * 16 + qm;
        af[i] = *(const short8*)&As[cb][r * 64 + ((s * 4 + quad) ^ (r & 7)) * 8];
      }
#pragma unroll
      for (int j = 0; j < 8; j++) {
        const int r = cw + j * 16 + qm;
        bfr[j] = *(const short8*)&Bs[cb][r * 64 + ((s * 4 + quad) ^ (r & 7)) * 8];
      }
      __builtin_amdgcn_s_setprio(1);
#pragma unroll
      for (int i = 0; i < 4; i++)
#pragma unroll
        for (int j = 0; j < 8; j++)
          acc[i][j] = __builtin_amdgcn_mfma_f32_16x16x32_bf16(af[i], bfr[j], acc[i][j], 0, 0, 0);
      __builtin_amdgcn_s_setprio(0);
    }
    if (t + 1 < NT)   // drain AFTER compute: nb fully written, latency hidden
      asm volatile("s_waitcnt vmcnt(0)" ::: "memory");
    __builtin_amdgcn_s_barrier();   // all waves done reading cb; nb published
  }

  // epilogue: partial logit = sum_j gelu(acc+b1)*W2; reduce over qm lanes; 1 atomic/row
  float w2j[8], bc[8];
#pragma unroll
  for (int j = 0; j < 8; j++) {
    const int col = n0 + cw + j * 16 + qm;
    w2j[j] = W2[col];
    bc[j] = b1[col];
  }
#pragma unroll
  for (int i = 0; i < 4; i++) {
#pragma unroll
    for (int r = 0; r < 4; r++) {
      float p = 0.0f;
#pragma unroll
      for (int j = 0; j < 8; j++)
        p += gelu_f(acc[i][j][r] + bc[j]) * w2j[j];
      p += __shfl_xor(p, 1);
      p += __shfl_xor(p, 2);
      p += __shfl_xor(p, 4);
      p += __shfl_xor(p, 8);
      if (qm == 0)
        atomicAdd(&logits[m0 + rw + i * 16 + quad * 4 + r], p);
    }
  }
}

// ---------- fused: fractional shift + window avg + l2norm(actx,v) + concat ----------
// v3: TAP-DEDUP within the proven grid-4096 structure. The 6 taps of row t
// read 7 consecutive a-rows (a1 of tap j == a0 of tap j+1); load each once
// into a sliding register. 12 -> 7 a-loads per lane (-42% of this kernel's
// dominant traffic), arithmetic bit-identical (same values, same tau-ascending
// add order). Rows t<11 (88 of 16384) keep the original clipped path.
__global__ __launch_bounds__(256) void shift_norm(const float* __restrict__ a,
                                                  const float* __restrict__ v,
                                                  float* __restrict__ actx,
                                                  u16* __restrict__ xb,
                                                  const float* __restrict__ theta) {
  const int row = blockIdx.x * 4 + (threadIdx.x >> 6);
  const int lane = threadIdx.x & 63;
  const int d4 = lane * 4;
  const int bb = row >> 11;
  const int t = row & (T_SEQ - 1);
  const float th = fminf(fmaxf(theta[0], -12.0f), 12.0f);
  const float delta = 2.0f + 4.0f * (1.0f / (1.0f + expf(-th)));
  const float dl = fminf(fmaxf(delta, 0.0f), (float)(T_SEQ - 1));
  const float nf = floorf(dl);
  const float alpha = dl - nf;
  const int ni = (int)nf;                        // 2..6
  const float* ab = a + (size_t)bb * T_SEQ * 256;
  float4 o;
  if (t >= 11) {
    // rows t-5-ni .. t+1-ni, all interior (t-5-ni >= 0, t+1-ni <= t-1)
    const float* base = ab + (size_t)(t - 5 - ni) * 256 + d4;
    float sx = 0, sy = 0, sz = 0, sw = 0;
    float4 prev = *(const float4*)base;
#pragma unroll
    for (int j = 0; j < 6; j++) {
      const float4 cur = *(const float4*)(base + (size_t)(j + 1) * 256);
      sx += prev.x + alpha * (cur.x - prev.x);
      sy += prev.y + alpha * (cur.y - prev.y);
      sz += prev.z + alpha * (cur.z - prev.z);
      sw += prev.w + alpha * (cur.w - prev.w);
      prev = cur;
    }
    const float sc = 1.0f / 6.0f;
    o.x = sx * sc; o.y = sy * sc; o.z = sz * sc; o.w = sw * sc;
  } else {
    const float center = fminf(fmaxf((float)t + delta, 0.0f), (float)t);
    float sx = 0, sy = 0, sz = 0, sw = 0, cnt = 0.0f;
#pragma unroll
    for (int j = 0; j < 6; j++) {
      const int tau = t - 5 + j;
      if (tau < 0) continue;
      if (fabsf((float)tau - center) > 5.0f) continue;
      cnt += 1.0f;
      const int i0 = min(max(tau - ni, 0), T_SEQ - 1);
      const int i1 = min(i0 + 1, T_SEQ - 1);
      const float4 a0 = *(const float4*)&ab[(size_t)i0 * 256 + d4];
      const float4 a1 = *(const float4*)&ab[(size_t)i1 * 256 + d4];
      sx += a0.x + alpha * (a1.x - a0.x);
      sy += a0.y + alpha * (a1.y - a0.y);
      sz += a0.z + alpha * (a1.z - a0.z);
      sw += a0.w + alpha * (a1.w - a0.w);
    }
    const float sc = 1.0f / fmaxf(cnt, 1e-8f);
    o.x = sx * sc; o.y = sy * sc; o.z = sz * sc; o.w = sw * sc;
  }
  *(float4*)&actx[(size_t)row * 256 + d4] = o;
  const float4 vv = *(const float4*)&v[(size_t)row * 256 + d4];
  float sa2 = o.x * o.x + o.y * o.y + o.z * o.z + o.w * o.w;
  float sv2 = vv.x * vv.x + vv.y * vv.y + vv.z * vv.z + vv.w * vv.w;
  sa2 = wave_bcast_sum(sa2);
  sv2 = wave_bcast_sum(sv2);
  const float ia = 1.0f / fmaxf(sqrtf(sa2), 1e-8f);
  const float iv = 1.0f / fmaxf(sqrtf(sv2), 1e-8f);
  const float anx = o.x * ia, any_ = o.y * ia, anz = o.z * ia, anw = o.w * ia;
  const float vnx = vv.x * iv, vny = vv.y * iv, vnz = vv.z * iv, vnw = vv.w * iv;
  u16* xr = xb + (size_t)row * 768;
  u32 pa[2] = {pkbf(anx, any_), pkbf(anz, anw)};
  u32 pv[2] = {pkbf(vnx, vny), pkbf(vnz, vnw)};
  u32 pp[2] = {pkbf(anx * vnx, any_ * vny), pkbf(anz * vnz, anw * vnw)};
  *(uint2*)&xr[d4] = *(uint2*)pa;
  *(uint2*)&xr[256 + d4] = *(uint2*)pv;
  *(uint2*)&xr[512 + d4] = *(uint2*)pp;
}

// ---------- gate + mix ----------
__global__ __launch_bounds__(256) void gate_mix(const float* __restrict__ logits,
                                                const float* __restrict__ b2,
                                                const float* __restrict__ actx,
                                                const float* __restrict__ v,
                                                float* __restrict__ out) {
  const int row = blockIdx.x * 4 + (threadIdx.x >> 6);
  const int lane = threadIdx.x & 63;
  const float l = fminf(fmaxf(logits[row] + b2[0], -12.0f), 12.0f);
  float g = 1.0f / (1.0f + expf(-l));
  g = fminf(fmaxf(g, 0.05f), 0.95f);
  const float4 aa = *(const float4*)&actx[(size_t)row * 256 + lane * 4];
  const float4 vv = *(const float4*)&v[(size_t)row * 256 + lane * 4];
  float4 o;
  o.x = g * aa.x + (1.0f - g) * vv.x;
  o.y = g * aa.y + (1.0f - g) * vv.y;
  o.z = g * aa.z + (1.0f - g) * vv.z;
  o.w = g * aa.w + (1.0f - g) * vv.w;
  *(float4*)&out[(size_t)row * 256 + lane * 4] = o;
}

// ---------- launch ----------
extern "C" void kernel_launch(void* const* d_in, const int* in_sizes, int n_in,
                              void* d_out, int out_size, void* d_ws, size_t ws_size,
                              hipStream_t stream) {
  const float* video = (const float*)d_in[0];
  const float* audio = (const float*)d_in[1];
  const float* Wv    = (const float*)d_in[2];
  const float* bv    = (const float*)d_in[3];
  const float* Wa    = (const float*)d_in[4];
  const float* ba    = (const float*)d_in[5];
  const float* theta = (const float*)d_in[6];
  const float* W1    = (const float*)d_in[7];
  const float* b1    = (const float*)d_in[8];
  const float* W2    = (const float*)d_in[9];
  const float* b2    = (const float*)d_in[10];
  float* out = (float*)d_out;
  char* ws = (char*)d_ws;

  const size_t OFF_WVT = 0;          // [256][1024] bf16 = 512 KB
  const size_t OFF_WAT = 524288;     // [256][768]  bf16 = 384 KB
  const size_t OFF_W1T = 917504;     // [1024][768] bf16 = 1.5 MB
  const size_t OFF_LOG = 2490368;    // [16384] f32 = 64 KB
  const size_t OFF_V   = 2555904;    // [16384][256] f32 = 16 MB (LN'd v)
  const size_t OFF_A   = 19333120;   // [16384][256] f32 = 16 MB (LN'd a)
  const size_t OFF_ACTX= 36110336;   // [16384][256] f32 = 16 MB
  const size_t OFF_XB  = 52887552;   // [16384][768] bf16 = 24 MB

  u16* wvT = (u16*)(ws + OFF_WVT);
  u16* waT = (u16*)(ws + OFF_WAT);
  u16* w1T = (u16*)(ws + OFF_W1T);
  float* logits = (float*)(ws + OFF_LOG);
  float* v    = (float*)(ws + OFF_V);
  float* a    = (float*)(ws + OFF_A);
  float* actx = (float*)(ws + OFF_ACTX);
  u16* xb = (u16*)(ws + OFF_XB);

  tcvt_all<<<1280, 256, 0, stream>>>(Wv, Wa, W1, wvT, waT, w1T, logits);
  proj_ln<<<512, 256, 0, stream>>>(video, audio, wvT, waT, bv, ba, v, a);
  shift_norm<<<BT_ROWS / 4, 256, 0, stream>>>(a, v, actx, xb, theta);
  gemm_gelu_w2<<<dim3(4, 64), 512, 0, stream>>>(xb, w1T, b1, W2, logits);
  gate_mix<<<BT_ROWS / 4, 256, 0, stream>>>(logits, b2, actx, v, out);
}